// Round 1
// baseline (278.607 us; speedup 1.0000x reference)
//
#include <hip/hip_runtime.h>
#include <hip/hip_bf16.h>

#define S_LEN 4096
#define DMODEL 512
#define NHEADS 8
#define HDIM 64

typedef __hip_bfloat16 bf16;
typedef __attribute__((ext_vector_type(8))) short bf16x8;
typedef __attribute__((ext_vector_type(4))) float f32x4;
typedef __attribute__((ext_vector_type(4))) _Float16 f16x4;
typedef __attribute__((ext_vector_type(8))) _Float16 f16x8;

__device__ __forceinline__ f32x4 mfma16x16x32(bf16x8 a, bf16x8 b, f32x4 c) {
    return __builtin_amdgcn_mfma_f32_16x16x32_bf16(a, b, c, 0, 0, 0);
}
__device__ __forceinline__ f32x4 mfma16x16x16h(f16x4 a, f16x4 b, f32x4 c) {
    return __builtin_amdgcn_mfma_f32_16x16x16f16(a, b, c, 0, 0, 0);
}
// async global->LDS, 16B per lane; LDS dest = wave-uniform base + lane*16
__device__ __forceinline__ void gload_lds16(const void* g, void* l) {
    __builtin_amdgcn_global_load_lds(
        (const __attribute__((address_space(1))) unsigned int*)g,
        (__attribute__((address_space(3))) unsigned int*)l, 16, 0, 0);
}

// ---------------------------------------------------------------------------
// fp32 -> bf16 elementwise convert (X matrix)
// ---------------------------------------------------------------------------
__global__ __launch_bounds__(256) void cvt_f32_bf16(
    const float* __restrict__ in, bf16* __restrict__ out, int n)
{
    int i = (blockIdx.x * 256 + threadIdx.x) * 8;
    if (i >= n) return;
    float4 a = *(const float4*)(in + i);
    float4 b = *(const float4*)(in + i + 4);
    bf16 tmp[8];
    tmp[0] = __float2bfloat16(a.x); tmp[1] = __float2bfloat16(a.y);
    tmp[2] = __float2bfloat16(a.z); tmp[3] = __float2bfloat16(a.w);
    tmp[4] = __float2bfloat16(b.x); tmp[5] = __float2bfloat16(b.y);
    tmp[6] = __float2bfloat16(b.z); tmp[7] = __float2bfloat16(b.w);
    *(bf16x8*)(out + i) = *(bf16x8*)tmp;
}

// ---------------------------------------------------------------------------
// Transpose+convert 4 512x512 fp32 weight matrices: out[n][k] = (bf16)in[k][n]
// ---------------------------------------------------------------------------
__global__ __launch_bounds__(256) void transpose_w(
    const float* __restrict__ Wq, const float* __restrict__ Wk,
    const float* __restrict__ Wv, const float* __restrict__ Wo,
    bf16* __restrict__ out)
{
    const float* src = (blockIdx.z == 0) ? Wq : (blockIdx.z == 1) ? Wk
                     : (blockIdx.z == 2) ? Wv : Wo;
    bf16* dst = out + (size_t)blockIdx.z * DMODEL * DMODEL;
    __shared__ bf16 tile[32][33];
    int tx = threadIdx.x, ty = threadIdx.y;
    int x = blockIdx.x * 32 + tx;
    int y0 = blockIdx.y * 32;
    #pragma unroll
    for (int i = ty; i < 32; i += 8)
        tile[i][tx] = __float2bfloat16(src[(size_t)(y0 + i) * DMODEL + x]);
    __syncthreads();
    int xo = y0 + tx;
    #pragma unroll
    for (int i = ty; i < 32; i += 8)
        dst[(size_t)(blockIdx.x * 32 + i) * DMODEL + xo] = tile[tx][i];
}

// ---------------------------------------------------------------------------
// Fused QKV projection, m97-style: 128x128 tile, BK=64, global_load_lds(16B).
// Y = X[4096,512] @ Wt[1536,512]^T
// n in [0,512)    -> Qm bf16, scaled (1/8)*log2(e)  (attn uses exp2)
// n in [512,1024) -> Km bf16
// n in [1024,1536)-> Vt  f16, stored transposed [512][4096]
// 4 waves (2x2), each computes a 64x64 sub-tile as 4x4 16x16 frags.
// ---------------------------------------------------------------------------
__global__ __launch_bounds__(256) void gemm_qkv(
    const bf16* __restrict__ A, const bf16* __restrict__ Bt,
    bf16* __restrict__ Qm, bf16* __restrict__ Km, _Float16* __restrict__ Vt)
{
    __shared__ __align__(16) bf16 As[128 * 64];
    __shared__ __align__(16) bf16 Bs[128 * 64];
    const int m0 = blockIdx.x * 128, n0 = blockIdx.y * 128;
    const int t = threadIdx.x, lane = t & 63, w = t >> 6;
    const int lr = lane & 15, lq = lane >> 4;
    const int wr = w >> 1, wc = w & 1;

    f32x4 acc[4][4];
    #pragma unroll
    for (int i = 0; i < 4; ++i)
        #pragma unroll
        for (int j = 0; j < 4; ++j) acc[i][j] = f32x4{0, 0, 0, 0};

    // staging: lane l covers row (l>>3), 16B col chunk (l&7); wave w rows w*32..+31
    const int srow = w * 32 + (lane >> 3);
    const int scol = (lane & 7) * 8;
    const bf16* Ab = A + (size_t)(m0 + srow) * DMODEL + scol;
    const bf16* Bb = Bt + (size_t)(n0 + srow) * DMODEL + scol;

    for (int k0 = 0; k0 < DMODEL; k0 += 64) {
        __syncthreads();
        #pragma unroll
        for (int i = 0; i < 4; ++i) {
            gload_lds16(Ab + (size_t)(i * 8) * DMODEL + k0, &As[(w * 32 + i * 8) * 64]);
            gload_lds16(Bb + (size_t)(i * 8) * DMODEL + k0, &Bs[(w * 32 + i * 8) * 64]);
        }
        __syncthreads();
        #pragma unroll
        for (int kc = 0; kc < 2; ++kc) {
            bf16x8 af[4], bfr[4];
            #pragma unroll
            for (int fq = 0; fq < 4; ++fq)
                af[fq] = *(const bf16x8*)&As[(wr * 64 + fq * 16 + lr) * 64 + kc * 32 + lq * 8];
            #pragma unroll
            for (int fr = 0; fr < 4; ++fr)
                bfr[fr] = *(const bf16x8*)&Bs[(wc * 64 + fr * 16 + lr) * 64 + kc * 32 + lq * 8];
            #pragma unroll
            for (int fq = 0; fq < 4; ++fq)
                #pragma unroll
                for (int fr = 0; fr < 4; ++fr)
                    acc[fq][fr] = mfma16x16x32(af[fq], bfr[fr], acc[fq][fr]);
        }
    }

    const int which = n0 >> 9;          // 0=Q 1=K 2=V
    const int nloc = n0 & 511;
    const int row0 = m0 + wr * 64 + lq * 4;     // output row base (+fq*16+r)
    const int col0 = nloc + wc * 64 + lr;       // output col base (+fr*16)
    if (which == 0) {
        #pragma unroll
        for (int fq = 0; fq < 4; ++fq)
            #pragma unroll
            for (int fr = 0; fr < 4; ++fr)
                #pragma unroll
                for (int r = 0; r < 4; ++r)
                    Qm[(size_t)(row0 + fq * 16 + r) * DMODEL + col0 + fr * 16] =
                        __float2bfloat16(acc[fq][fr][r] * 0.18033688f);  // (1/8)*log2e
    } else if (which == 1) {
        #pragma unroll
        for (int fq = 0; fq < 4; ++fq)
            #pragma unroll
            for (int fr = 0; fr < 4; ++fr)
                #pragma unroll
                for (int r = 0; r < 4; ++r)
                    Km[(size_t)(row0 + fq * 16 + r) * DMODEL + col0 + fr * 16] =
                        __float2bfloat16(acc[fq][fr][r]);
    } else {
        // V^T: the 4 accumulator rows are contiguous columns of Vt -> f16x4 store
        #pragma unroll
        for (int fq = 0; fq < 4; ++fq)
            #pragma unroll
            for (int fr = 0; fr < 4; ++fr) {
                _Float16 tmp[4];
                #pragma unroll
                for (int r = 0; r < 4; ++r) tmp[r] = (_Float16)acc[fq][fr][r];
                *(f16x4*)(Vt + (size_t)(col0 + fr * 16) * S_LEN + row0 + fq * 16) =
                    *(f16x4*)tmp;
            }
    }
}

// ---------------------------------------------------------------------------
// Out projection, same 128x128 structure: out = AO @ Wot^T + bias, fp32 out.
// ---------------------------------------------------------------------------
__global__ __launch_bounds__(256) void gemm_out(
    const bf16* __restrict__ A, const bf16* __restrict__ Bt,
    float* __restrict__ Out, const float* __restrict__ bias)
{
    __shared__ __align__(16) bf16 As[128 * 64];
    __shared__ __align__(16) bf16 Bs[128 * 64];
    const int m0 = blockIdx.x * 128, n0 = blockIdx.y * 128;
    const int t = threadIdx.x, lane = t & 63, w = t >> 6;
    const int lr = lane & 15, lq = lane >> 4;
    const int wr = w >> 1, wc = w & 1;

    f32x4 acc[4][4];
    #pragma unroll
    for (int i = 0; i < 4; ++i)
        #pragma unroll
        for (int j = 0; j < 4; ++j) acc[i][j] = f32x4{0, 0, 0, 0};

    const int srow = w * 32 + (lane >> 3);
    const int scol = (lane & 7) * 8;
    const bf16* Ab = A + (size_t)(m0 + srow) * DMODEL + scol;
    const bf16* Bb = Bt + (size_t)(n0 + srow) * DMODEL + scol;

    for (int k0 = 0; k0 < DMODEL; k0 += 64) {
        __syncthreads();
        #pragma unroll
        for (int i = 0; i < 4; ++i) {
            gload_lds16(Ab + (size_t)(i * 8) * DMODEL + k0, &As[(w * 32 + i * 8) * 64]);
            gload_lds16(Bb + (size_t)(i * 8) * DMODEL + k0, &Bs[(w * 32 + i * 8) * 64]);
        }
        __syncthreads();
        #pragma unroll
        for (int kc = 0; kc < 2; ++kc) {
            bf16x8 af[4], bfr[4];
            #pragma unroll
            for (int fq = 0; fq < 4; ++fq)
                af[fq] = *(const bf16x8*)&As[(wr * 64 + fq * 16 + lr) * 64 + kc * 32 + lq * 8];
            #pragma unroll
            for (int fr = 0; fr < 4; ++fr)
                bfr[fr] = *(const bf16x8*)&Bs[(wc * 64 + fr * 16 + lr) * 64 + kc * 32 + lq * 8];
            #pragma unroll
            for (int fq = 0; fq < 4; ++fq)
                #pragma unroll
                for (int fr = 0; fr < 4; ++fr)
                    acc[fq][fr] = mfma16x16x32(af[fq], bfr[fr], acc[fq][fr]);
        }
    }

    const int row0 = m0 + wr * 64 + lq * 4;
    const int col0 = n0 + wc * 64 + lr;
    #pragma unroll
    for (int fq = 0; fq < 4; ++fq)
        #pragma unroll
        for (int fr = 0; fr < 4; ++fr)
            #pragma unroll
            for (int r = 0; r < 4; ++r)
                Out[(size_t)(row0 + fq * 16 + r) * DMODEL + col0 + fr * 16] =
                    acc[fq][fr][r] + bias[col0 + fr * 16];
}

// ---------------------------------------------------------------------------
// Attention, wave-decoupled kt-split. grid (H, S/32) so linear block id % 8
// == head -> each XCD serves ONE head (1 MB K+V slice is L2-resident).
// 32 Q rows/block (2 qt tiles), 4 waves: wave w handles kt = w, w+4, ...
// => 1024 blocks = 4 blocks/CU = 4 waves/SIMD (2x the old occupancy).
// exp2-no-max softmax (Q pre-scaled by (1/8)*log2e); wave partials combine
// linearly in a one-time LDS epilogue. NO LDS/barriers in the main loop.
// ---------------------------------------------------------------------------
__global__ __launch_bounds__(256, 4) void attn_kernel(
    const bf16* __restrict__ Q, const bf16* __restrict__ Kmat,
    const _Float16* __restrict__ Vt, bf16* __restrict__ Oout)
{
    __shared__ __align__(16) float obuf[4][2][4][64][4];  // 32 KB: [wave][qt][ht][lane][4]
    __shared__ float lbuf[4][2][16];                      // 512 B: [wave][qt][lr]

    const int h = blockIdx.x, qb = blockIdx.y;
    const int t = threadIdx.x, lane = t & 63, w = t >> 6;
    const int lr = lane & 15, lq = lane >> 4;
    const int q0 = qb * 32;

    // Q B-frags for both qt tiles (B[n=lr][k=lq*8+j])
    bf16x8 qf[2][2];
    #pragma unroll
    for (int qt = 0; qt < 2; ++qt) {
        const bf16* qp = Q + (size_t)(q0 + qt * 16 + lr) * DMODEL + h * HDIM + lq * 8;
        qf[qt][0] = *(const bf16x8*)qp;
        qf[qt][1] = *(const bf16x8*)(qp + 32);
    }

    f32x4 oacc[2][4];   // [qt][ht]; C: row(Q)=lq*4+r, col(hd)=lr
    #pragma unroll
    for (int i = 0; i < 2; ++i)
        #pragma unroll
        for (int j = 0; j < 4; ++j) oacc[i][j] = f32x4{0, 0, 0, 0};
    float lsum[2] = {0, 0};

    for (int kt = w; kt < S_LEN / 64; kt += 4) {
        // K A-frags (A[m=lr][k=lq*8+j]), 16B gathers (L2-hit: head-local XCD)
        const bf16* kb = Kmat + (size_t)(kt * 64) * DMODEL + h * HDIM;
        bf16x8 kf[4][2];
        #pragma unroll
        for (int mt = 0; mt < 4; ++mt) {
            const bf16* kp = kb + (size_t)(mt * 16 + lr) * DMODEL + lq * 8;
            kf[mt][0] = *(const bf16x8*)kp;
            kf[mt][1] = *(const bf16x8*)(kp + 32);
        }
        // V^T B-frags (B[n=hd=lr][k=Kidx=lq*4+j]), 8B gathers
        f16x4 vf[4][4];   // [mt][ht]
        #pragma unroll
        for (int ht = 0; ht < 4; ++ht) {
            const _Float16* vp = Vt + (size_t)(h * HDIM + ht * 16 + lr) * S_LEN + kt * 64 + lq * 4;
            #pragma unroll
            for (int mt = 0; mt < 4; ++mt)
                vf[mt][ht] = *(const f16x4*)(vp + mt * 16);
        }
        // S^T = K @ Q^T ; P = exp2(S^T)  (log2e folded into Q)
        f16x4 pf[2][4];   // [qt][mt]; A-frag: A[m=Q=lr][k=lq*4+j]
        #pragma unroll
        for (int qt = 0; qt < 2; ++qt) {
            f32x4 st[4];
            #pragma unroll
            for (int mt = 0; mt < 4; ++mt) {
                f32x4 z = {0, 0, 0, 0};
                z = mfma16x16x32(kf[mt][0], qf[qt][0], z);
                z = mfma16x16x32(kf[mt][1], qf[qt][1], z);
                st[mt] = z;
            }
            #pragma unroll
            for (int mt = 0; mt < 4; ++mt)
                #pragma unroll
                for (int r = 0; r < 4; ++r) {
                    float p = __builtin_amdgcn_exp2f(st[mt][r]);
                    lsum[qt] += p;
                    pf[qt][mt][r] = (_Float16)p;
                }
        }
        // O += P @ V
        #pragma unroll
        for (int qt = 0; qt < 2; ++qt)
            #pragma unroll
            for (int ht = 0; ht < 4; ++ht)
                #pragma unroll
                for (int mt = 0; mt < 4; ++mt)
                    oacc[qt][ht] = mfma16x16x16h(pf[qt][mt], vf[mt][ht], oacc[qt][ht]);
    }

    // ---- cross-wave combine (linear: no max-rescale needed) ----
    // wave qt (qt<2) finalizes tile qt; everyone publishes non-finalized slots
    #pragma unroll
    for (int qt = 0; qt < 2; ++qt) {
        if (w != qt) {
            #pragma unroll
            for (int ht = 0; ht < 4; ++ht)
                *(f32x4*)&obuf[w][qt][ht][lane][0] = oacc[qt][ht];
        }
    }
    #pragma unroll
    for (int qt = 0; qt < 2; ++qt) {
        float s = lsum[qt];
        s += __shfl_xor(s, 16);
        s += __shfl_xor(s, 32);
        if (lq == 0) lbuf[w][qt][lr] = s;
    }
    __syncthreads();

    if (w < 2) {
        const int qt = w;
        f32x4 osum[4];
        #pragma unroll
        for (int ht = 0; ht < 4; ++ht) osum[ht] = oacc[qt][ht];
        #pragma unroll
        for (int w2 = 0; w2 < 4; ++w2) {
            if (w2 == qt) continue;
            #pragma unroll
            for (int ht = 0; ht < 4; ++ht)
                osum[ht] += *(const f32x4*)&obuf[w2][qt][ht][lane][0];
        }
        float linv[4];
        #pragma unroll
        for (int r = 0; r < 4; ++r) {
            int rr = lq * 4 + r;
            linv[r] = 1.0f / (lbuf[0][qt][rr] + lbuf[1][qt][rr] + lbuf[2][qt][rr] + lbuf[3][qt][rr]);
        }
        #pragma unroll
        for (int r = 0; r < 4; ++r) {
            int row = q0 + qt * 16 + lq * 4 + r;
            #pragma unroll
            for (int ht = 0; ht < 4; ++ht)
                Oout[(size_t)row * DMODEL + h * HDIM + ht * 16 + lr] =
                    __float2bfloat16(osum[ht][r] * linv[r]);
        }
    }
}

// ---------------------------------------------------------------------------
extern "C" void kernel_launch(void* const* d_in, const int* in_sizes, int n_in,
                              void* d_out, int out_size, void* d_ws, size_t ws_size,
                              hipStream_t stream) {
    const float* X  = (const float*)d_in[0];
    const float* Wq = (const float*)d_in[1];
    const float* Wk = (const float*)d_in[2];
    const float* Wv = (const float*)d_in[3];
    const float* Wo = (const float*)d_in[4];
    const float* bo = (const float*)d_in[5];
    float* out = (float*)d_out;

    char* ws = (char*)d_ws;
    bf16* Wt = (bf16*)ws;                                  // [4][512][512] bf16
    bf16* Xb = (bf16*)(ws + (size_t)4 * DMODEL * DMODEL * 2);
    bf16* Qm = Xb + (size_t)S_LEN * DMODEL;
    bf16* Km = Qm + (size_t)S_LEN * DMODEL;
    _Float16* Vt = (_Float16*)(Km + (size_t)S_LEN * DMODEL);   // [512][4096] f16
    bf16* AO = (bf16*)(Vt + (size_t)S_LEN * DMODEL);

    bf16* Wot = Wt + (size_t)3 * DMODEL * DMODEL;

    int nX = S_LEN * DMODEL;
    cvt_f32_bf16<<<nX / (256 * 8), 256, 0, stream>>>(X, Xb, nX);
    transpose_w<<<dim3(16, 16, 4), dim3(32, 8), 0, stream>>>(Wq, Wk, Wv, Wo, Wt);

    gemm_qkv<<<dim3(S_LEN / 128, 3 * DMODEL / 128), 256, 0, stream>>>(
        Xb, Wt, Qm, Km, Vt);

    attn_kernel<<<dim3(NHEADS, S_LEN / 32), 256, 0, stream>>>(Qm, Km, Vt, AO);

    gemm_out<<<dim3(S_LEN / 128, DMODEL / 128), 256, 0, stream>>>(AO, Wot, out, bo);
}

// Round 2
// 192.163 us; speedup vs baseline: 1.4498x; 1.4498x over previous
//
#include <hip/hip_runtime.h>
#include <hip/hip_bf16.h>

#define S_LEN 4096
#define DMODEL 512
#define NHEADS 8
#define HDIM 64

typedef __hip_bfloat16 bf16;
typedef __attribute__((ext_vector_type(8))) short bf16x8;
typedef __attribute__((ext_vector_type(4))) float f32x4;
typedef __attribute__((ext_vector_type(4))) _Float16 f16x4;
typedef __attribute__((ext_vector_type(8))) _Float16 f16x8;

__device__ __forceinline__ f32x4 mfma16x16x32(bf16x8 a, bf16x8 b, f32x4 c) {
    return __builtin_amdgcn_mfma_f32_16x16x32_bf16(a, b, c, 0, 0, 0);
}
__device__ __forceinline__ f32x4 mfma16x16x16h(f16x4 a, f16x4 b, f32x4 c) {
    return __builtin_amdgcn_mfma_f32_16x16x16f16(a, b, c, 0, 0, 0);
}
// async global->LDS, 16B per lane; LDS dest = wave-uniform base + lane*16
__device__ __forceinline__ void gload_lds16(const void* g, void* l) {
    __builtin_amdgcn_global_load_lds(
        (const __attribute__((address_space(1))) unsigned int*)g,
        (__attribute__((address_space(3))) unsigned int*)l, 16, 0, 0);
}

// ---------------------------------------------------------------------------
// fp32 -> bf16 elementwise convert (X matrix)
// ---------------------------------------------------------------------------
__global__ __launch_bounds__(256) void cvt_f32_bf16(
    const float* __restrict__ in, bf16* __restrict__ out, int n)
{
    int i = (blockIdx.x * 256 + threadIdx.x) * 8;
    if (i >= n) return;
    float4 a = *(const float4*)(in + i);
    float4 b = *(const float4*)(in + i + 4);
    bf16 tmp[8];
    tmp[0] = __float2bfloat16(a.x); tmp[1] = __float2bfloat16(a.y);
    tmp[2] = __float2bfloat16(a.z); tmp[3] = __float2bfloat16(a.w);
    tmp[4] = __float2bfloat16(b.x); tmp[5] = __float2bfloat16(b.y);
    tmp[6] = __float2bfloat16(b.z); tmp[7] = __float2bfloat16(b.w);
    *(bf16x8*)(out + i) = *(bf16x8*)tmp;
}

// ---------------------------------------------------------------------------
// Transpose+convert 4 512x512 fp32 weight matrices: out[n][k] = (bf16)in[k][n]
// ---------------------------------------------------------------------------
__global__ __launch_bounds__(256) void transpose_w(
    const float* __restrict__ Wq, const float* __restrict__ Wk,
    const float* __restrict__ Wv, const float* __restrict__ Wo,
    bf16* __restrict__ out)
{
    const float* src = (blockIdx.z == 0) ? Wq : (blockIdx.z == 1) ? Wk
                     : (blockIdx.z == 2) ? Wv : Wo;
    bf16* dst = out + (size_t)blockIdx.z * DMODEL * DMODEL;
    __shared__ bf16 tile[32][33];
    int tx = threadIdx.x, ty = threadIdx.y;
    int x = blockIdx.x * 32 + tx;
    int y0 = blockIdx.y * 32;
    #pragma unroll
    for (int i = ty; i < 32; i += 8)
        tile[i][tx] = __float2bfloat16(src[(size_t)(y0 + i) * DMODEL + x]);
    __syncthreads();
    int xo = y0 + tx;
    #pragma unroll
    for (int i = ty; i < 32; i += 8)
        dst[(size_t)(blockIdx.x * 32 + i) * DMODEL + xo] = tile[tx][i];
}

// ---------------------------------------------------------------------------
// Fused QKV projection, m97-style: 128x128 tile, BK=64, global_load_lds(16B).
// Y = X[4096,512] @ Wt[1536,512]^T
// n in [0,512)    -> Qm bf16, scaled (1/8)*log2(e)  (attn uses exp2)
// n in [512,1024) -> Km bf16
// n in [1024,1536)-> Vt  f16, stored transposed [512][4096]
// ---------------------------------------------------------------------------
__global__ __launch_bounds__(256) void gemm_qkv(
    const bf16* __restrict__ A, const bf16* __restrict__ Bt,
    bf16* __restrict__ Qm, bf16* __restrict__ Km, _Float16* __restrict__ Vt)
{
    __shared__ __align__(16) bf16 As[128 * 64];
    __shared__ __align__(16) bf16 Bs[128 * 64];
    const int m0 = blockIdx.x * 128, n0 = blockIdx.y * 128;
    const int t = threadIdx.x, lane = t & 63, w = t >> 6;
    const int lr = lane & 15, lq = lane >> 4;
    const int wr = w >> 1, wc = w & 1;

    f32x4 acc[4][4];
    #pragma unroll
    for (int i = 0; i < 4; ++i)
        #pragma unroll
        for (int j = 0; j < 4; ++j) acc[i][j] = f32x4{0, 0, 0, 0};

    const int srow = w * 32 + (lane >> 3);
    const int scol = (lane & 7) * 8;
    const bf16* Ab = A + (size_t)(m0 + srow) * DMODEL + scol;
    const bf16* Bb = Bt + (size_t)(n0 + srow) * DMODEL + scol;

    for (int k0 = 0; k0 < DMODEL; k0 += 64) {
        __syncthreads();
        #pragma unroll
        for (int i = 0; i < 4; ++i) {
            gload_lds16(Ab + (size_t)(i * 8) * DMODEL + k0, &As[(w * 32 + i * 8) * 64]);
            gload_lds16(Bb + (size_t)(i * 8) * DMODEL + k0, &Bs[(w * 32 + i * 8) * 64]);
        }
        __syncthreads();
        #pragma unroll
        for (int kc = 0; kc < 2; ++kc) {
            bf16x8 af[4], bfr[4];
            #pragma unroll
            for (int fq = 0; fq < 4; ++fq)
                af[fq] = *(const bf16x8*)&As[(wr * 64 + fq * 16 + lr) * 64 + kc * 32 + lq * 8];
            #pragma unroll
            for (int fr = 0; fr < 4; ++fr)
                bfr[fr] = *(const bf16x8*)&Bs[(wc * 64 + fr * 16 + lr) * 64 + kc * 32 + lq * 8];
            #pragma unroll
            for (int fq = 0; fq < 4; ++fq)
                #pragma unroll
                for (int fr = 0; fr < 4; ++fr)
                    acc[fq][fr] = mfma16x16x32(af[fq], bfr[fr], acc[fq][fr]);
        }
    }

    const int which = n0 >> 9;          // 0=Q 1=K 2=V
    const int nloc = n0 & 511;
    const int row0 = m0 + wr * 64 + lq * 4;     // output row base (+fq*16+r)
    const int col0 = nloc + wc * 64 + lr;       // output col base (+fr*16)
    if (which == 0) {
        #pragma unroll
        for (int fq = 0; fq < 4; ++fq)
            #pragma unroll
            for (int fr = 0; fr < 4; ++fr)
                #pragma unroll
                for (int r = 0; r < 4; ++r)
                    Qm[(size_t)(row0 + fq * 16 + r) * DMODEL + col0 + fr * 16] =
                        __float2bfloat16(acc[fq][fr][r] * 0.18033688f);  // (1/8)*log2e
    } else if (which == 1) {
        #pragma unroll
        for (int fq = 0; fq < 4; ++fq)
            #pragma unroll
            for (int fr = 0; fr < 4; ++fr)
                #pragma unroll
                for (int r = 0; r < 4; ++r)
                    Km[(size_t)(row0 + fq * 16 + r) * DMODEL + col0 + fr * 16] =
                        __float2bfloat16(acc[fq][fr][r]);
    } else {
        // V^T: the 4 accumulator rows are contiguous columns of Vt -> f16x4 store
        #pragma unroll
        for (int fq = 0; fq < 4; ++fq)
            #pragma unroll
            for (int fr = 0; fr < 4; ++fr) {
                _Float16 tmp[4];
                #pragma unroll
                for (int r = 0; r < 4; ++r) tmp[r] = (_Float16)acc[fq][fr][r];
                *(f16x4*)(Vt + (size_t)(col0 + fr * 16) * S_LEN + row0 + fq * 16) =
                    *(f16x4*)tmp;
            }
    }
}

// ---------------------------------------------------------------------------
// Out projection, same 128x128 structure: out = AO @ Wot^T + bias, fp32 out.
// ---------------------------------------------------------------------------
__global__ __launch_bounds__(256) void gemm_out(
    const bf16* __restrict__ A, const bf16* __restrict__ Bt,
    float* __restrict__ Out, const float* __restrict__ bias)
{
    __shared__ __align__(16) bf16 As[128 * 64];
    __shared__ __align__(16) bf16 Bs[128 * 64];
    const int m0 = blockIdx.x * 128, n0 = blockIdx.y * 128;
    const int t = threadIdx.x, lane = t & 63, w = t >> 6;
    const int lr = lane & 15, lq = lane >> 4;
    const int wr = w >> 1, wc = w & 1;

    f32x4 acc[4][4];
    #pragma unroll
    for (int i = 0; i < 4; ++i)
        #pragma unroll
        for (int j = 0; j < 4; ++j) acc[i][j] = f32x4{0, 0, 0, 0};

    const int srow = w * 32 + (lane >> 3);
    const int scol = (lane & 7) * 8;
    const bf16* Ab = A + (size_t)(m0 + srow) * DMODEL + scol;
    const bf16* Bb = Bt + (size_t)(n0 + srow) * DMODEL + scol;

    for (int k0 = 0; k0 < DMODEL; k0 += 64) {
        __syncthreads();
        #pragma unroll
        for (int i = 0; i < 4; ++i) {
            gload_lds16(Ab + (size_t)(i * 8) * DMODEL + k0, &As[(w * 32 + i * 8) * 64]);
            gload_lds16(Bb + (size_t)(i * 8) * DMODEL + k0, &Bs[(w * 32 + i * 8) * 64]);
        }
        __syncthreads();
        #pragma unroll
        for (int kc = 0; kc < 2; ++kc) {
            bf16x8 af[4], bfr[4];
            #pragma unroll
            for (int fq = 0; fq < 4; ++fq)
                af[fq] = *(const bf16x8*)&As[(wr * 64 + fq * 16 + lr) * 64 + kc * 32 + lq * 8];
            #pragma unroll
            for (int fr = 0; fr < 4; ++fr)
                bfr[fr] = *(const bf16x8*)&Bs[(wc * 64 + fr * 16 + lr) * 64 + kc * 32 + lq * 8];
            #pragma unroll
            for (int fq = 0; fq < 4; ++fq)
                #pragma unroll
                for (int fr = 0; fr < 4; ++fr)
                    acc[fq][fr] = mfma16x16x32(af[fq], bfr[fr], acc[fq][fr]);
        }
    }

    const int row0 = m0 + wr * 64 + lq * 4;
    const int col0 = n0 + wc * 64 + lr;
    #pragma unroll
    for (int fq = 0; fq < 4; ++fq)
        #pragma unroll
        for (int fr = 0; fr < 4; ++fr)
            #pragma unroll
            for (int r = 0; r < 4; ++r)
                Out[(size_t)(row0 + fq * 16 + r) * DMODEL + col0 + fr * 16] =
                    acc[fq][fr][r] + bias[col0 + fr * 16];
}

// ---------------------------------------------------------------------------
// Attention, wave-decoupled kt-split. 64 Q rows/block (round-0 structure:
// fits in ~120 VGPR, no spill). grid (H, S/64) so linear block id % 8 == head
// -> each XCD serves ONE head; its 1 MB K+V slice stays L2-resident
// (proven round 1: FETCH 34.9 MB -> 6.5 MB).
// Wave w handles kt = w, w+4, ... (16 tiles each), for ALL 64 Q rows.
// exp2-no-max softmax (Q pre-scaled by (1/8)*log2e) => wave partials
// (oacc, lsum) combine linearly in a one-time LDS epilogue.
// NO LDS, NO barriers in main loop.
// ---------------------------------------------------------------------------
__global__ __launch_bounds__(256, 2) void attn_kernel(
    const bf16* __restrict__ Q, const bf16* __restrict__ Kmat,
    const _Float16* __restrict__ Vt, bf16* __restrict__ Oout)
{
    __shared__ __align__(16) float obuf[4][3][4][64][4];  // 48 KB: [wave][slot][ht][lane][4]
    __shared__ float lbuf[4][4][16];                      // 1 KB: [wave][qt][lr]

    const int h = blockIdx.x, qb = blockIdx.y;
    const int t = threadIdx.x, lane = t & 63, w = t >> 6;
    const int lr = lane & 15, lq = lane >> 4;
    const int q0 = qb * 64;

    // Q B-frags for all 4 qt tiles (B[n=lr][k=lq*8+j])
    bf16x8 qf[4][2];
    #pragma unroll
    for (int qt = 0; qt < 4; ++qt) {
        const bf16* qp = Q + (size_t)(q0 + qt * 16 + lr) * DMODEL + h * HDIM + lq * 8;
        qf[qt][0] = *(const bf16x8*)qp;
        qf[qt][1] = *(const bf16x8*)(qp + 32);
    }

    f32x4 oacc[4][4];   // [qt][ht]; C: row(Q)=lq*4+r, col(hd)=lr
    #pragma unroll
    for (int i = 0; i < 4; ++i)
        #pragma unroll
        for (int j = 0; j < 4; ++j) oacc[i][j] = f32x4{0, 0, 0, 0};
    float lsum[4] = {0, 0, 0, 0};

    for (int kt = w; kt < S_LEN / 64; kt += 4) {
        // K A-frags (A[m=lr][k=lq*8+j]), 16B gathers (L2-hit: head-local XCD)
        const bf16* kb = Kmat + (size_t)(kt * 64) * DMODEL + h * HDIM;
        bf16x8 kf[4][2];
        #pragma unroll
        for (int mt = 0; mt < 4; ++mt) {
            const bf16* kp = kb + (size_t)(mt * 16 + lr) * DMODEL + lq * 8;
            kf[mt][0] = *(const bf16x8*)kp;
            kf[mt][1] = *(const bf16x8*)(kp + 32);
        }
        // V^T B-frags (B[n=hd=lr][k=Kidx=lq*4+j]), 8B gathers
        f16x4 vf[4][4];   // [mt][ht]
        #pragma unroll
        for (int ht = 0; ht < 4; ++ht) {
            const _Float16* vp = Vt + (size_t)(h * HDIM + ht * 16 + lr) * S_LEN + kt * 64 + lq * 4;
            #pragma unroll
            for (int mt = 0; mt < 4; ++mt)
                vf[mt][ht] = *(const f16x4*)(vp + mt * 16);
        }
        // S^T = K @ Q^T ; P = exp2(S^T)  (log2e folded into Q)
        f16x4 pf[4][4];   // [qt][mt]; A-frag of 16x16x16: A[m=Q=lr][k=lq*4+j]
        #pragma unroll
        for (int qt = 0; qt < 4; ++qt) {
            f32x4 st[4];
            #pragma unroll
            for (int mt = 0; mt < 4; ++mt) {
                f32x4 z = {0, 0, 0, 0};
                z = mfma16x16x32(kf[mt][0], qf[qt][0], z);
                z = mfma16x16x32(kf[mt][1], qf[qt][1], z);
                st[mt] = z;
            }
            #pragma unroll
            for (int mt = 0; mt < 4; ++mt)
                #pragma unroll
                for (int r = 0; r < 4; ++r) {
                    float p = __builtin_amdgcn_exp2f(st[mt][r]);
                    lsum[qt] += p;
                    pf[qt][mt][r] = (_Float16)p;
                }
        }
        // O += P @ V
        #pragma unroll
        for (int qt = 0; qt < 4; ++qt)
            #pragma unroll
            for (int ht = 0; ht < 4; ++ht)
                #pragma unroll
                for (int mt = 0; mt < 4; ++mt)
                    oacc[qt][ht] = mfma16x16x16h(pf[qt][mt], vf[mt][ht], oacc[qt][ht]);
    }

    // ---- cross-wave combine (linear: no max-rescale needed) ----
    // publish non-own qt tiles (slot j = qt - (qt>w))
    #pragma unroll
    for (int qt = 0; qt < 4; ++qt) {
        if (qt != w) {
            int j = qt - (qt > w ? 1 : 0);
            #pragma unroll
            for (int ht = 0; ht < 4; ++ht)
                *(f32x4*)&obuf[w][j][ht][lane][0] = oacc[qt][ht];
        }
    }
    // row sums: reduce over lq groups, publish
    #pragma unroll
    for (int qt = 0; qt < 4; ++qt) {
        float s = lsum[qt];
        s += __shfl_xor(s, 16);
        s += __shfl_xor(s, 32);
        if (lq == 0) lbuf[w][qt][lr] = s;
    }
    __syncthreads();

    // wave w finalizes qt == w
    f32x4 osum[4];
    #pragma unroll
    for (int qt = 0; qt < 4; ++qt)
        if (qt == w) {
            #pragma unroll
            for (int ht = 0; ht < 4; ++ht) osum[ht] = oacc[qt][ht];
        }
    #pragma unroll
    for (int w2 = 0; w2 < 4; ++w2) {
        if (w2 == w) continue;
        int j = w - (w > w2 ? 1 : 0);
        #pragma unroll
        for (int ht = 0; ht < 4; ++ht)
            osum[ht] += *(const f32x4*)&obuf[w2][j][ht][lane][0];
    }
    float linv[4];
    #pragma unroll
    for (int r = 0; r < 4; ++r) {
        int rr = lq * 4 + r;
        linv[r] = 1.0f / (lbuf[0][w][rr] + lbuf[1][w][rr] + lbuf[2][w][rr] + lbuf[3][w][rr]);
    }
    #pragma unroll
    for (int r = 0; r < 4; ++r) {
        int row = q0 + w * 16 + lq * 4 + r;
        #pragma unroll
        for (int ht = 0; ht < 4; ++ht)
            Oout[(size_t)row * DMODEL + h * HDIM + ht * 16 + lr] =
                __float2bfloat16(osum[ht][r] * linv[r]);
    }
}

// ---------------------------------------------------------------------------
extern "C" void kernel_launch(void* const* d_in, const int* in_sizes, int n_in,
                              void* d_out, int out_size, void* d_ws, size_t ws_size,
                              hipStream_t stream) {
    const float* X  = (const float*)d_in[0];
    const float* Wq = (const float*)d_in[1];
    const float* Wk = (const float*)d_in[2];
    const float* Wv = (const float*)d_in[3];
    const float* Wo = (const float*)d_in[4];
    const float* bo = (const float*)d_in[5];
    float* out = (float*)d_out;

    char* ws = (char*)d_ws;
    bf16* Wt = (bf16*)ws;                                  // [4][512][512] bf16
    bf16* Xb = (bf16*)(ws + (size_t)4 * DMODEL * DMODEL * 2);
    bf16* Qm = Xb + (size_t)S_LEN * DMODEL;
    bf16* Km = Qm + (size_t)S_LEN * DMODEL;
    _Float16* Vt = (_Float16*)(Km + (size_t)S_LEN * DMODEL);   // [512][4096] f16
    bf16* AO = (bf16*)(Vt + (size_t)S_LEN * DMODEL);

    bf16* Wot = Wt + (size_t)3 * DMODEL * DMODEL;

    int nX = S_LEN * DMODEL;
    cvt_f32_bf16<<<nX / (256 * 8), 256, 0, stream>>>(X, Xb, nX);
    transpose_w<<<dim3(16, 16, 4), dim3(32, 8), 0, stream>>>(Wq, Wk, Wv, Wo, Wt);

    gemm_qkv<<<dim3(S_LEN / 128, 3 * DMODEL / 128), 256, 0, stream>>>(
        Xb, Wt, Qm, Km, Vt);

    attn_kernel<<<dim3(NHEADS, S_LEN / 64), 256, 0, stream>>>(Qm, Km, Vt, AO);

    gemm_out<<<dim3(S_LEN / 128, DMODEL / 128), 256, 0, stream>>>(AO, Wot, out, bo);
}

// Round 3
// 139.549 us; speedup vs baseline: 1.9965x; 1.3770x over previous
//
#include <hip/hip_runtime.h>
#include <hip/hip_bf16.h>

#define S_LEN 4096
#define DMODEL 512
#define NHEADS 8
#define HDIM 64

typedef __hip_bfloat16 bf16;
typedef __attribute__((ext_vector_type(8))) short bf16x8;
typedef __attribute__((ext_vector_type(4))) float f32x4;
typedef __attribute__((ext_vector_type(4))) _Float16 f16x4;
typedef __attribute__((ext_vector_type(8))) _Float16 f16x8;

__device__ __forceinline__ f32x4 mfma16x16x32(bf16x8 a, bf16x8 b, f32x4 c) {
    return __builtin_amdgcn_mfma_f32_16x16x32_bf16(a, b, c, 0, 0, 0);
}
__device__ __forceinline__ f32x4 mfma16x16x16h(f16x4 a, f16x4 b, f32x4 c) {
    return __builtin_amdgcn_mfma_f32_16x16x16f16(a, b, c, 0, 0, 0);
}
// async global->LDS, 16B per lane; LDS dest = wave-uniform base + lane*16,
// global source is PER-LANE.
__device__ __forceinline__ void gload_lds16(const void* g, void* l) {
    __builtin_amdgcn_global_load_lds(
        (const __attribute__((address_space(1))) unsigned int*)g,
        (__attribute__((address_space(3))) unsigned int*)l, 16, 0, 0);
}

// ---------------------------------------------------------------------------
// Prep: fused X fp32->bf16 convert (blocks 0..1023) and W transpose+convert
// (blocks 1024..2047). One launch instead of two.
// ---------------------------------------------------------------------------
__global__ __launch_bounds__(256) void prep(
    const float* __restrict__ X,
    const float* __restrict__ Wq, const float* __restrict__ Wk,
    const float* __restrict__ Wv, const float* __restrict__ Wo,
    bf16* __restrict__ Xb, bf16* __restrict__ Wt)
{
    __shared__ bf16 tile[32][33];
    const int b = blockIdx.x;
    if (b < 1024) {
        int i = (b * 256 + threadIdx.x) * 8;
        float4 a = *(const float4*)(X + i);
        float4 c = *(const float4*)(X + i + 4);
        bf16 tmp[8];
        tmp[0] = __float2bfloat16(a.x); tmp[1] = __float2bfloat16(a.y);
        tmp[2] = __float2bfloat16(a.z); tmp[3] = __float2bfloat16(a.w);
        tmp[4] = __float2bfloat16(c.x); tmp[5] = __float2bfloat16(c.y);
        tmp[6] = __float2bfloat16(c.z); tmp[7] = __float2bfloat16(c.w);
        *(bf16x8*)(Xb + i) = *(bf16x8*)tmp;
    } else {
        const int bb = b - 1024;
        const int z = bb >> 8;
        const int bx = bb & 15, by = (bb >> 4) & 15;
        const float* src = (z == 0) ? Wq : (z == 1) ? Wk : (z == 2) ? Wv : Wo;
        bf16* dst = Wt + (size_t)z * DMODEL * DMODEL;
        const int tx = threadIdx.x & 31, ty = threadIdx.x >> 5;
        const int x = bx * 32 + tx;
        const int y0 = by * 32;
        #pragma unroll
        for (int i = ty; i < 32; i += 8)
            tile[i][tx] = __float2bfloat16(src[(size_t)(y0 + i) * DMODEL + x]);
        __syncthreads();
        const int xo = y0 + tx;
        #pragma unroll
        for (int i = ty; i < 32; i += 8)
            dst[(size_t)(bx * 32 + i) * DMODEL + xo] = tile[tx][i];
    }
}

// ---------------------------------------------------------------------------
// Fused QKV projection, m97-style: 128x128 tile, BK=64, global_load_lds(16B).
// Y = X[4096,512] @ Wt[1536,512]^T
// n in [0,512)    -> Qm bf16, scaled (1/8)*log2(e)  (attn uses exp2)
// n in [512,1024) -> Km bf16
// n in [1024,1536)-> Vt  f16, stored transposed [512][4096]
// ---------------------------------------------------------------------------
__global__ __launch_bounds__(256) void gemm_qkv(
    const bf16* __restrict__ A, const bf16* __restrict__ Bt,
    bf16* __restrict__ Qm, bf16* __restrict__ Km, _Float16* __restrict__ Vt)
{
    __shared__ __align__(16) bf16 As[128 * 64];
    __shared__ __align__(16) bf16 Bs[128 * 64];
    const int m0 = blockIdx.x * 128, n0 = blockIdx.y * 128;
    const int t = threadIdx.x, lane = t & 63, w = t >> 6;
    const int lr = lane & 15, lq = lane >> 4;
    const int wr = w >> 1, wc = w & 1;

    f32x4 acc[4][4];
    #pragma unroll
    for (int i = 0; i < 4; ++i)
        #pragma unroll
        for (int j = 0; j < 4; ++j) acc[i][j] = f32x4{0, 0, 0, 0};

    const int srow = w * 32 + (lane >> 3);
    const int scol = (lane & 7) * 8;
    const bf16* Ab = A + (size_t)(m0 + srow) * DMODEL + scol;
    const bf16* Bb = Bt + (size_t)(n0 + srow) * DMODEL + scol;

    for (int k0 = 0; k0 < DMODEL; k0 += 64) {
        __syncthreads();
        #pragma unroll
        for (int i = 0; i < 4; ++i) {
            gload_lds16(Ab + (size_t)(i * 8) * DMODEL + k0, &As[(w * 32 + i * 8) * 64]);
            gload_lds16(Bb + (size_t)(i * 8) * DMODEL + k0, &Bs[(w * 32 + i * 8) * 64]);
        }
        __syncthreads();
        #pragma unroll
        for (int kc = 0; kc < 2; ++kc) {
            bf16x8 af[4], bfr[4];
            #pragma unroll
            for (int fq = 0; fq < 4; ++fq)
                af[fq] = *(const bf16x8*)&As[(wr * 64 + fq * 16 + lr) * 64 + kc * 32 + lq * 8];
            #pragma unroll
            for (int fr = 0; fr < 4; ++fr)
                bfr[fr] = *(const bf16x8*)&Bs[(wc * 64 + fr * 16 + lr) * 64 + kc * 32 + lq * 8];
            #pragma unroll
            for (int fq = 0; fq < 4; ++fq)
                #pragma unroll
                for (int fr = 0; fr < 4; ++fr)
                    acc[fq][fr] = mfma16x16x32(af[fq], bfr[fr], acc[fq][fr]);
        }
    }

    const int which = n0 >> 9;          // 0=Q 1=K 2=V
    const int nloc = n0 & 511;
    const int row0 = m0 + wr * 64 + lq * 4;     // output row base (+fq*16+r)
    const int col0 = nloc + wc * 64 + lr;       // output col base (+fr*16)
    if (which == 0) {
        #pragma unroll
        for (int fq = 0; fq < 4; ++fq)
            #pragma unroll
            for (int fr = 0; fr < 4; ++fr)
                #pragma unroll
                for (int r = 0; r < 4; ++r)
                    Qm[(size_t)(row0 + fq * 16 + r) * DMODEL + col0 + fr * 16] =
                        __float2bfloat16(acc[fq][fr][r] * 0.18033688f);  // (1/8)*log2e
    } else if (which == 1) {
        #pragma unroll
        for (int fq = 0; fq < 4; ++fq)
            #pragma unroll
            for (int fr = 0; fr < 4; ++fr)
                #pragma unroll
                for (int r = 0; r < 4; ++r)
                    Km[(size_t)(row0 + fq * 16 + r) * DMODEL + col0 + fr * 16] =
                        __float2bfloat16(acc[fq][fr][r]);
    } else {
        // V^T: the 4 accumulator rows are contiguous columns of Vt -> f16x4 store
        #pragma unroll
        for (int fq = 0; fq < 4; ++fq)
            #pragma unroll
            for (int fr = 0; fr < 4; ++fr) {
                _Float16 tmp[4];
                #pragma unroll
                for (int r = 0; r < 4; ++r) tmp[r] = (_Float16)acc[fq][fr][r];
                *(f16x4*)(Vt + (size_t)(col0 + fr * 16) * S_LEN + row0 + fq * 16) =
                    *(f16x4*)tmp;
            }
    }
}

// ---------------------------------------------------------------------------
// Out projection, same 128x128 structure: out = AO @ Wot^T + bias, fp32 out.
// ---------------------------------------------------------------------------
__global__ __launch_bounds__(256) void gemm_out(
    const bf16* __restrict__ A, const bf16* __restrict__ Bt,
    float* __restrict__ Out, const float* __restrict__ bias)
{
    __shared__ __align__(16) bf16 As[128 * 64];
    __shared__ __align__(16) bf16 Bs[128 * 64];
    const int m0 = blockIdx.x * 128, n0 = blockIdx.y * 128;
    const int t = threadIdx.x, lane = t & 63, w = t >> 6;
    const int lr = lane & 15, lq = lane >> 4;
    const int wr = w >> 1, wc = w & 1;

    f32x4 acc[4][4];
    #pragma unroll
    for (int i = 0; i < 4; ++i)
        #pragma unroll
        for (int j = 0; j < 4; ++j) acc[i][j] = f32x4{0, 0, 0, 0};

    const int srow = w * 32 + (lane >> 3);
    const int scol = (lane & 7) * 8;
    const bf16* Ab = A + (size_t)(m0 + srow) * DMODEL + scol;
    const bf16* Bb = Bt + (size_t)(n0 + srow) * DMODEL + scol;

    for (int k0 = 0; k0 < DMODEL; k0 += 64) {
        __syncthreads();
        #pragma unroll
        for (int i = 0; i < 4; ++i) {
            gload_lds16(Ab + (size_t)(i * 8) * DMODEL + k0, &As[(w * 32 + i * 8) * 64]);
            gload_lds16(Bb + (size_t)(i * 8) * DMODEL + k0, &Bs[(w * 32 + i * 8) * 64]);
        }
        __syncthreads();
        #pragma unroll
        for (int kc = 0; kc < 2; ++kc) {
            bf16x8 af[4], bfr[4];
            #pragma unroll
            for (int fq = 0; fq < 4; ++fq)
                af[fq] = *(const bf16x8*)&As[(wr * 64 + fq * 16 + lr) * 64 + kc * 32 + lq * 8];
            #pragma unroll
            for (int fr = 0; fr < 4; ++fr)
                bfr[fr] = *(const bf16x8*)&Bs[(wc * 64 + fr * 16 + lr) * 64 + kc * 32 + lq * 8];
            #pragma unroll
            for (int fq = 0; fq < 4; ++fq)
                #pragma unroll
                for (int fr = 0; fr < 4; ++fr)
                    acc[fq][fr] = mfma16x16x32(af[fq], bfr[fr], acc[fq][fr]);
        }
    }

    const int row0 = m0 + wr * 64 + lq * 4;
    const int col0 = n0 + wc * 64 + lr;
    #pragma unroll
    for (int fq = 0; fq < 4; ++fq)
        #pragma unroll
        for (int fr = 0; fr < 4; ++fr)
            #pragma unroll
            for (int r = 0; r < 4; ++r)
                Out[(size_t)(row0 + fq * 16 + r) * DMODEL + col0 + fr * 16] =
                    acc[fq][fr][r] + bias[col0 + fr * 16];
}

// ---------------------------------------------------------------------------
// Attention v3: wave-decoupled kt-split (no barriers in main loop) +
// per-wave LDS staging of K/V tiles via coalesced global_load_lds(16B),
// XOR-swizzled ((row&7)<<4) applied on the GLOBAL SOURCE side (linear LDS
// dest) and on the ds_read side -- rule #21 both-sides involution.
// Single buffer + issue-early prefetch: read frags -> lgkmcnt(0) ->
// issue next tile's global_load_lds -> compute (hides staging latency) ->
// vmcnt(0) at loop top.
// grid (H, S/64): linear block id % 8 == head -> per-XCD L2-resident K/V
// (proven: FETCH 34.9 -> 6.2 MB). LDS 64KB/block (2 blocks/CU); epilogue
// obuf aliases the staging region behind a __syncthreads().
// ---------------------------------------------------------------------------
__global__ __launch_bounds__(256, 2) void attn_kernel(
    const bf16* __restrict__ Q, const bf16* __restrict__ Kmat,
    const _Float16* __restrict__ Vt, bf16* __restrict__ Oout)
{
    __shared__ __align__(16) char smem[65536];  // 4 waves x (8KB K + 8KB V); epilogue aliases

    const int h = blockIdx.x, qb = blockIdx.y;
    const int t = threadIdx.x, lane = t & 63, w = t >> 6;
    const int lr = lane & 15, lq = lane >> 4;
    const int q0 = qb * 64;

    char* myK = smem + w * 16384;       // [64 rows][128B]  K tile (bf16)
    char* myV = myK + 8192;             // [64 hd  ][128B]  V^T tile (f16)

    // staging lane geometry: lane covers row (lane>>3) in each 8-row group,
    // 16B chunk (lane&7) XOR-swizzled by row&7 (= lane>>3 since groups are 8)
    const int sr = lane >> 3;
    const int scc = (lane & 7) ^ sr;                 // pre-swizzled global chunk
    const bf16*     gK = Kmat + (size_t)sr * DMODEL + h * HDIM + scc * 8;
    const _Float16* gV = Vt + (size_t)(h * HDIM + sr) * S_LEN + scc * 8;

    // Q B-frags for all 4 qt tiles (one-time scattered loads)
    bf16x8 qf[4][2];
    #pragma unroll
    for (int qt = 0; qt < 4; ++qt) {
        const bf16* qp = Q + (size_t)(q0 + qt * 16 + lr) * DMODEL + h * HDIM + lq * 8;
        qf[qt][0] = *(const bf16x8*)qp;
        qf[qt][1] = *(const bf16x8*)(qp + 32);
    }

    f32x4 oacc[4][4];   // [qt][ht]; C: row(Q)=lq*4+r, col(hd)=lr
    #pragma unroll
    for (int i = 0; i < 4; ++i)
        #pragma unroll
        for (int j = 0; j < 4; ++j) oacc[i][j] = f32x4{0, 0, 0, 0};
    float lsum[4] = {0, 0, 0, 0};

    // prologue: stage first tile (kt = w)
    #pragma unroll
    for (int i = 0; i < 8; ++i) {
        gload_lds16(gK + (size_t)(w * 64 + i * 8) * DMODEL, myK + i * 1024);
        gload_lds16(gV + (size_t)(i * 8) * S_LEN + w * 64, myV + i * 1024);
    }

    const int swz = (lr & 7) << 4;

    for (int kt = w; kt < S_LEN / 64; kt += 4) {
        asm volatile("s_waitcnt vmcnt(0)" ::: "memory");  // staged tile landed

        // K frags from LDS (swizzled ds_read_b128, conflict-free)
        bf16x8 kf[4][2];
        #pragma unroll
        for (int mt = 0; mt < 4; ++mt) {
            const char* kr = myK + (mt * 16 + lr) * 128;
            kf[mt][0] = *(const bf16x8*)(kr + ((lq * 16) ^ swz));
            kf[mt][1] = *(const bf16x8*)(kr + ((64 + lq * 16) ^ swz));
        }
        // V^T frags from LDS (swizzled ds_read_b64, conflict-free)
        f16x4 vf[4][4];   // [mt][ht]
        #pragma unroll
        for (int ht = 0; ht < 4; ++ht) {
            const char* vr = myV + (ht * 16 + lr) * 128;
            #pragma unroll
            for (int mt = 0; mt < 4; ++mt)
                vf[mt][ht] = *(const f16x4*)(vr + ((mt * 32 + lq * 8) ^ swz));
        }
        // all frag reads complete before re-staging overwrites the buffer
        asm volatile("s_waitcnt lgkmcnt(0)" ::: "memory");
        __builtin_amdgcn_sched_barrier(0);

        // issue-early prefetch of next tile (overlaps with compute below)
        const int ktn = kt + 4;
        if (ktn < S_LEN / 64) {
            #pragma unroll
            for (int i = 0; i < 8; ++i) {
                gload_lds16(gK + (size_t)(ktn * 64 + i * 8) * DMODEL, myK + i * 1024);
                gload_lds16(gV + (size_t)(i * 8) * S_LEN + ktn * 64, myV + i * 1024);
            }
        }

        __builtin_amdgcn_s_setprio(1);
        // S^T = K @ Q^T ; P = exp2(S^T)  (log2e folded into Q)
        f16x4 pf[4][4];   // [qt][mt]; A-frag of 16x16x16: A[m=Q=lr][k=lq*4+j]
        #pragma unroll
        for (int qt = 0; qt < 4; ++qt) {
            f32x4 st[4];
            #pragma unroll
            for (int mt = 0; mt < 4; ++mt) {
                f32x4 z = {0, 0, 0, 0};
                z = mfma16x16x32(kf[mt][0], qf[qt][0], z);
                z = mfma16x16x32(kf[mt][1], qf[qt][1], z);
                st[mt] = z;
            }
            #pragma unroll
            for (int mt = 0; mt < 4; ++mt)
                #pragma unroll
                for (int r = 0; r < 4; ++r) {
                    float p = __builtin_amdgcn_exp2f(st[mt][r]);
                    lsum[qt] += p;
                    pf[qt][mt][r] = (_Float16)p;
                }
        }
        // O += P @ V
        #pragma unroll
        for (int qt = 0; qt < 4; ++qt)
            #pragma unroll
            for (int ht = 0; ht < 4; ++ht)
                #pragma unroll
                for (int mt = 0; mt < 4; ++mt)
                    oacc[qt][ht] = mfma16x16x16h(pf[qt][mt], vf[mt][ht], oacc[qt][ht]);
        __builtin_amdgcn_s_setprio(0);
    }

    // ---- cross-wave combine; obuf ALIASES the staging LDS ----
    __syncthreads();   // all waves done reading their staging regions
    float (*obuf)[3][4][64][4] = (float(*)[3][4][64][4])smem;   // 48KB
    float (*lbuf)[4][16]       = (float(*)[4][16])(smem + 49152);

    #pragma unroll
    for (int qt = 0; qt < 4; ++qt) {
        if (qt != w) {
            int j = qt - (qt > w ? 1 : 0);
            #pragma unroll
            for (int ht = 0; ht < 4; ++ht)
                *(f32x4*)&obuf[w][j][ht][lane][0] = oacc[qt][ht];
        }
    }
    #pragma unroll
    for (int qt = 0; qt < 4; ++qt) {
        float s = lsum[qt];
        s += __shfl_xor(s, 16);
        s += __shfl_xor(s, 32);
        if (lq == 0) lbuf[w][qt][lr] = s;
    }
    __syncthreads();

    // wave w finalizes qt == w
    f32x4 osum[4];
    #pragma unroll
    for (int qt = 0; qt < 4; ++qt)
        if (qt == w) {
            #pragma unroll
            for (int ht = 0; ht < 4; ++ht) osum[ht] = oacc[qt][ht];
        }
    #pragma unroll
    for (int w2 = 0; w2 < 4; ++w2) {
        if (w2 == w) continue;
        int j = w - (w > w2 ? 1 : 0);
        #pragma unroll
        for (int ht = 0; ht < 4; ++ht)
            osum[ht] += *(const f32x4*)&obuf[w2][j][ht][lane][0];
    }
    float linv[4];
    #pragma unroll
    for (int r = 0; r < 4; ++r) {
        int rr = lq * 4 + r;
        linv[r] = 1.0f / (lbuf[0][w][rr] + lbuf[1][w][rr] + lbuf[2][w][rr] + lbuf[3][w][rr]);
    }
    #pragma unroll
    for (int r = 0; r < 4; ++r) {
        int row = q0 + w * 16 + lq * 4 + r;
        #pragma unroll
        for (int ht = 0; ht < 4; ++ht)
            Oout[(size_t)row * DMODEL + h * HDIM + ht * 16 + lr] =
                __float2bfloat16(osum[ht][r] * linv[r]);
    }
}

// ---------------------------------------------------------------------------
extern "C" void kernel_launch(void* const* d_in, const int* in_sizes, int n_in,
                              void* d_out, int out_size, void* d_ws, size_t ws_size,
                              hipStream_t stream) {
    const float* X  = (const float*)d_in[0];
    const float* Wq = (const float*)d_in[1];
    const float* Wk = (const float*)d_in[2];
    const float* Wv = (const float*)d_in[3];
    const float* Wo = (const float*)d_in[4];
    const float* bo = (const float*)d_in[5];
    float* out = (float*)d_out;

    char* ws = (char*)d_ws;
    bf16* Wt = (bf16*)ws;                                  // [4][512][512] bf16
    bf16* Xb = (bf16*)(ws + (size_t)4 * DMODEL * DMODEL * 2);
    bf16* Qm = Xb + (size_t)S_LEN * DMODEL;
    bf16* Km = Qm + (size_t)S_LEN * DMODEL;
    _Float16* Vt = (_Float16*)(Km + (size_t)S_LEN * DMODEL);   // [512][4096] f16
    bf16* AO = (bf16*)(Vt + (size_t)S_LEN * DMODEL);

    bf16* Wot = Wt + (size_t)3 * DMODEL * DMODEL;

    prep<<<2048, 256, 0, stream>>>(X, Wq, Wk, Wv, Wo, Xb, Wt);

    gemm_qkv<<<dim3(S_LEN / 128, 3 * DMODEL / 128), 256, 0, stream>>>(
        Xb, Wt, Qm, Km, Vt);

    attn_kernel<<<dim3(NHEADS, S_LEN / 64), 256, 0, stream>>>(Qm, Km, Vt, AO);

    gemm_out<<<dim3(S_LEN / 128, DMODEL / 128), 256, 0, stream>>>(AO, Wot, out, bo);
}